// Round 10
// baseline (998.480 us; speedup 1.0000x reference)
//
#include <hip/hip_runtime.h>
#include <hip/hip_cooperative_groups.h>
#include <math.h>

#define D 256        // embedding dim
#define P 128        // projection dim
#define K 8192       // num embeddings
#define NTOK 16384   // 16*1024 tokens
#define NROWS (NTOK + K)
#define CAPC 64              // candidate slots per token (expect ~20-40)
#define MARGIN 3.0f          // >> 2*bf16 distance error
#define FLT_BIG 3.402823466e+38f
#define GRID 512

typedef __attribute__((ext_vector_type(8))) short bf16x8;
typedef __attribute__((ext_vector_type(4))) float f32x4;
typedef __attribute__((ext_vector_type(8))) unsigned short u16x8;

__device__ __forceinline__ unsigned short f32_to_bf16_rne(float f) {
    unsigned int u = __float_as_uint(f);
    u = (u + 0x7fffu + ((u >> 16) & 1u)) >> 16;
    return (unsigned short)u;
}

// ---------------------------------------------------------------------------
// ONE cooperative kernel, 4 phases separated by grid syncs.
//   P0: zero one-hot output (512 MB)      P1: projection (bit-identical math)
//   P2: bf16 MFMA filter -> candidates    P3: exact fp32 rescore + outputs
// ---------------------------------------------------------------------------
__global__ __launch_bounds__(256, 2) void mega_kernel(
    const float* __restrict__ x, const float* __restrict__ cb,
    const float* __restrict__ w, const float* __restrict__ bias,
    float* __restrict__ xproj, float* __restrict__ cproj,
    float* __restrict__ xnorm, float* __restrict__ cnorm,
    unsigned short* __restrict__ xh, unsigned short* __restrict__ chs,
    int* __restrict__ cnt, int* __restrict__ cand,
    float* __restrict__ discrete, float* __restrict__ quant)
{
    cooperative_groups::grid_group grid = cooperative_groups::this_grid();

    __shared__ float As[16][D];   // phase 1 staging (16 KB)
    __shared__ int sidx[32];      // phase 3

    const int tid = threadIdx.x;
    const int bid = blockIdx.x;
    const int lane = tid & 63;
    const int wave = tid >> 6;
    const int quad = lane >> 4;
    const int l15 = lane & 15;

    // ---------------- Phase 0: zero the one-hot matrix + init cnt ----------
    {
        f32x4* p = (f32x4*)discrete;
        const f32x4 zv = (f32x4)(0.f);
        size_t i = (size_t)bid * 256 + tid;
        const size_t n4 = (size_t)NTOK * K / 4;          // 33.5M
        for (; i < n4; i += (size_t)GRID * 256) p[i] = zv;
        int g = bid * 256 + tid;
        if (g < NTOK) cnt[g] = 0;
    }

    // ---------------- Phase 1: projection (3 units of 16 rows per block) ---
    for (int u = bid; u < NROWS / 16; u += GRID) {
        const int row0 = u * 16;
        __syncthreads();   // As safe to overwrite
        for (int i = tid; i < 16 * (D / 4); i += 256) {
            int r = i / (D / 4);
            int c4 = i % (D / 4);
            int gr = row0 + r;
            const float* src = (gr < NTOK) ? (x + (size_t)gr * D)
                                           : (cb + (size_t)(gr - NTOK) * D);
            float4 v = ((const float4*)src)[c4];
            ((float4*)&As[r][0])[c4] = v;
        }
        __syncthreads();

        const int r = tid >> 4;
        const int c0 = (tid & 15) * 8;

        float acc[8];
#pragma unroll
        for (int j = 0; j < 8; j++) acc[j] = 0.f;

        for (int d = 0; d < D; d += 4) {
            float4 a4 = *(const float4*)&As[r][d];
#pragma unroll
            for (int dd = 0; dd < 4; dd++) {
                float av = (dd == 0) ? a4.x : (dd == 1) ? a4.y : (dd == 2) ? a4.z : a4.w;
                float4 w0 = *(const float4*)&w[(size_t)(d + dd) * P + c0];
                float4 w1 = *(const float4*)&w[(size_t)(d + dd) * P + c0 + 4];
                acc[0] = fmaf(av, w0.x, acc[0]);
                acc[1] = fmaf(av, w0.y, acc[1]);
                acc[2] = fmaf(av, w0.z, acc[2]);
                acc[3] = fmaf(av, w0.w, acc[3]);
                acc[4] = fmaf(av, w1.x, acc[4]);
                acc[5] = fmaf(av, w1.y, acc[5]);
                acc[6] = fmaf(av, w1.z, acc[6]);
                acc[7] = fmaf(av, w1.w, acc[7]);
            }
        }

        float out[8];
        float nrm = 0.f;
        u16x8 hv;
#pragma unroll
        for (int j = 0; j < 8; j++) {
            out[j] = acc[j] + bias[c0 + j];
            nrm = fmaf(out[j], out[j], nrm);
            hv[j] = f32_to_bf16_rne(out[j]);
        }

        const int gr = row0 + r;
        float4 o0; o0.x = out[0]; o0.y = out[1]; o0.z = out[2]; o0.w = out[3];
        float4 o1; o1.x = out[4]; o1.y = out[5]; o1.z = out[6]; o1.w = out[7];
        if (gr < NTOK) {
            float* dst = xproj + (size_t)gr * P;
            *(float4*)&dst[c0] = o0;
            *(float4*)&dst[c0 + 4] = o1;
            *(u16x8*)(xh + (size_t)gr * P + c0) = hv;
        } else {
            int row = gr - NTOK;
            float* dst = cproj + (size_t)row * P;
            *(float4*)&dst[c0] = o0;
            *(float4*)&dst[c0 + 4] = o1;
            int t64 = row >> 6, rg = (row >> 4) & 3, rl = row & 15;
            int ks = c0 >> 5, q = (c0 >> 3) & 3;
            size_t atom = ((size_t)(t64 * 16 + rg * 4 + ks) * 4 + q) * 16 + rl;
            *(u16x8*)(chs + atom * 8) = hv;
        }

#pragma unroll
        for (int off = 1; off < 16; off <<= 1)
            nrm += __shfl_xor(nrm, off, 16);
        if ((tid & 15) == 0) {
            if (gr < NTOK) xnorm[gr] = nrm;
            else           cnorm[gr - NTOK] = nrm;
        }
    }

    grid.sync();

    // ---------------- Phase 2: bf16 MFMA filter ----------------------------
    // Block = (token-group g of 64 tokens) x (half h of the codebook, 4096).
    // Wave w owns 16 tokens; loops 64 tiles of 64 codes; running-min
    // threshold (monotone within the half); emits candidates (superset of
    // fp32 argmin: d_bf16(k*) <= run_min + 2eps < run_min + MARGIN).
    {
        const int g = bid >> 1;
        const int h = bid & 1;
        const int tok0 = g * 64;
        const int trow = tok0 + wave * 16;          // this wave's 16 tokens

        bf16x8 afrag[4];
#pragma unroll
        for (int ks = 0; ks < 4; ks++)
            afrag[ks] = *(const bf16x8*)(xh + (size_t)(trow + l15) * P + ks * 32 + quad * 8);

        float xnv[4];
#pragma unroll
        for (int r = 0; r < 4; r++)
            xnv[r] = xnorm[trow + quad * 4 + r];

        float rmin[4];
#pragma unroll
        for (int r = 0; r < 4; r++) rmin[r] = FLT_BIG;

        for (int ct = 0; ct < 64; ct++) {
            const int kt = h * 4096 + ct * 64;
            const int t64 = kt >> 6;

            f32x4 acc[4];
#pragma unroll
            for (int nj = 0; nj < 4; nj++) acc[nj] = (f32x4)(0.f);

#pragma unroll
            for (int ks = 0; ks < 4; ks++) {
                const bf16x8* base = (const bf16x8*)(chs) + (size_t)(t64 * 16 + ks) * 64 + lane;
                bf16x8 b0 = base[0 * 4 * 64];
                bf16x8 b1 = base[1 * 4 * 64];
                bf16x8 b2 = base[2 * 4 * 64];
                bf16x8 b3 = base[3 * 4 * 64];
                acc[0] = __builtin_amdgcn_mfma_f32_16x16x32_bf16(afrag[ks], b0, acc[0], 0, 0, 0);
                acc[1] = __builtin_amdgcn_mfma_f32_16x16x32_bf16(afrag[ks], b1, acc[1], 0, 0, 0);
                acc[2] = __builtin_amdgcn_mfma_f32_16x16x32_bf16(afrag[ks], b2, acc[2], 0, 0, 0);
                acc[3] = __builtin_amdgcn_mfma_f32_16x16x32_bf16(afrag[ks], b3, acc[3], 0, 0, 0);
            }

            float cn[4];
#pragma unroll
            for (int nj = 0; nj < 4; nj++) cn[nj] = cnorm[kt + nj * 16 + l15];

#pragma unroll
            for (int r = 0; r < 4; r++) {
                float d[4];
#pragma unroll
                for (int nj = 0; nj < 4; nj++)
                    d[nj] = (xnv[r] - 2.0f * acc[nj][r]) + cn[nj];
                float m = fminf(fminf(d[0], d[1]), fminf(d[2], d[3]));
#pragma unroll
                for (int off = 1; off < 16; off <<= 1)
                    m = fminf(m, __shfl_xor(m, off));
                float rm = fminf(rmin[r], m);
                rmin[r] = rm;
                float thr = rm + MARGIN;
                const int tok = trow + quad * 4 + r;
#pragma unroll
                for (int nj = 0; nj < 4; nj++) {
                    if (d[nj] <= thr) {
                        int pos = atomicAdd(&cnt[tok], 1);
                        if (pos < CAPC) cand[(size_t)tok * CAPC + pos] = kt + nj * 16 + l15;
                    }
                }
            }
        }
    }

    grid.sync();

    // ---------------- Phase 3: exact fp32 rescore + outputs ----------------
    // Block = 32 tokens; wave w handles 8 tokens sequentially, lanes parallel
    // over candidates. Packed u64 (dist_bits<<32|k) argmin: dist>0 so fp32
    // bits are order-monotone; tie -> lower idx (= jnp.argmin).
    {
        const int tok0 = bid * 32;
        for (int i = 0; i < 8; i++) {
            const int t = tok0 + wave * 8 + i;
            int n = cnt[t];
            if (n > CAPC) n = CAPC;
            const float xn = xnorm[t];
            const float* xr = xproj + (size_t)t * P;

            unsigned long long pack = 0xFFFFFFFFFFFFFFFFull;
            for (int j = lane; j < n; j += 64) {
                int k = cand[(size_t)t * CAPC + j];
                const float* cr = cproj + (size_t)k * P;
                float s = 0.f;
#pragma unroll 8
                for (int p = 0; p < P; p += 4) {
                    float4 a = *(const float4*)&xr[p];
                    float4 b = *(const float4*)&cr[p];
                    s = fmaf(a.x, b.x, s);
                    s = fmaf(a.y, b.y, s);
                    s = fmaf(a.z, b.z, s);
                    s = fmaf(a.w, b.w, s);
                }
                float dist = (xn - 2.0f * s) + cnorm[k];
                unsigned long long pk =
                    ((unsigned long long)__float_as_uint(dist) << 32) |
                    (unsigned long long)(unsigned)k;
                if (pk < pack) pack = pk;
            }
#pragma unroll
            for (int off = 1; off < 64; off <<= 1) {
                unsigned long long o = __shfl_xor((long long)pack, off);
                if (o < pack) pack = o;
            }
            if (lane == 0) {
                int bi = (int)(pack & 0xFFFFFFFFull);
                sidx[wave * 8 + i] = bi;
                discrete[(size_t)t * K + bi] = 1.0f;
            }
        }
        __syncthreads();

        for (int i = tid; i < 32 * (D / 4); i += 256) {
            int t = i >> 6;
            int c4 = i & 63;
            int bi = sidx[t];
            float4 v = ((const float4*)(cb + (size_t)bi * D))[c4];
            ((float4*)(quant + (size_t)(tok0 + t) * D))[c4] = v;
        }
    }
}

// ---------------------------------------------------------------------------
extern "C" void kernel_launch(void* const* d_in, const int* in_sizes, int n_in,
                              void* d_out, int out_size, void* d_ws, size_t ws_size,
                              hipStream_t stream) {
    const float* x    = (const float*)d_in[0];   // [16,1024,256]
    const float* cb   = (const float*)d_in[1];   // [8192,256]
    const float* w    = (const float*)d_in[2];   // [256,128]
    const float* bias = (const float*)d_in[3];   // [128]

    float* out = (float*)d_out;
    float* discrete = out;                               // [16384, 8192]
    float* quant = out + (size_t)NTOK * K;               // [16384, 256]

    char* ws = (char*)d_ws;
    size_t off = 0;
    float* xproj = (float*)(ws + off); off += (size_t)NTOK * P * 4;
    float* cproj = (float*)(ws + off); off += (size_t)K * P * 4;
    float* xnorm = (float*)(ws + off); off += (size_t)NTOK * 4;
    float* cnorm = (float*)(ws + off); off += (size_t)K * 4;
    unsigned short* xh  = (unsigned short*)(ws + off); off += (size_t)NTOK * P * 2;
    unsigned short* chs = (unsigned short*)(ws + off); off += (size_t)K * P * 2;
    int* cnt  = (int*)(ws + off); off += (size_t)NTOK * 4;
    int* cand = (int*)(ws + off); off += (size_t)NTOK * CAPC * 4;

    void* args[] = {
        (void*)&x, (void*)&cb, (void*)&w, (void*)&bias,
        (void*)&xproj, (void*)&cproj, (void*)&xnorm, (void*)&cnorm,
        (void*)&xh, (void*)&chs, (void*)&cnt, (void*)&cand,
        (void*)&discrete, (void*)&quant
    };
    hipLaunchCooperativeKernel((void*)mega_kernel, dim3(GRID), dim3(256),
                               args, 0, stream);
}

// Round 12
// 871.411 us; speedup vs baseline: 1.1458x; 1.1458x over previous
//
#include <hip/hip_runtime.h>
#include <math.h>

#define D 256        // embedding dim
#define P 128        // projection dim
#define K 8192       // num embeddings
#define NTOK 16384   // 16*1024 tokens
#define NROWS (NTOK + K)
#define CAPC 64              // candidate slots per token (expect ~1-3)
#define MARGIN 3.0f          // >> 2*bf16 distance error
#define FLT_BIG 3.402823466e+38f

typedef __attribute__((ext_vector_type(8))) short bf16x8;
typedef __attribute__((ext_vector_type(4))) float f32x4;
typedef __attribute__((ext_vector_type(8))) unsigned short u16x8;

__device__ __forceinline__ unsigned short f32_to_bf16_rne(float f) {
    unsigned int u = __float_as_uint(f);
    u = (u + 0x7fffu + ((u >> 16) & 1u)) >> 16;
    return (unsigned short)u;
}

// ---------------------------------------------------------------------------
// Kernel 1: fused projection (proven rounds 3-10). fp32 proj + norms; bf16
// copies (xh row-major; chs in MFMA-fragment-contiguous order). Inits
// cnt[] and gmin[].  ARITHMETIC ORDER UNCHANGED.
// ---------------------------------------------------------------------------
__global__ __launch_bounds__(256) void proj_kernel(
    const float* __restrict__ x, const float* __restrict__ cb,
    const float* __restrict__ w, const float* __restrict__ bias,
    float* __restrict__ xproj, float* __restrict__ cproj,
    float* __restrict__ xnorm, float* __restrict__ cnorm,
    unsigned short* __restrict__ xh, unsigned short* __restrict__ chs,
    int* __restrict__ cnt, int* __restrict__ gmin)
{
    __shared__ float As[16][D];   // 16 KB
    const int tid = threadIdx.x;
    const int row0 = blockIdx.x * 16;

    {   // init counters + global-min slots (ws is poisoned each call)
        int g = blockIdx.x * 256 + tid;
        if (g < NTOK) { cnt[g] = 0; gmin[g] = 0x7F7FFFFF; }   // FLT_MAX bits
    }

    for (int i = tid; i < 16 * (D / 4); i += 256) {
        int r = i / (D / 4);
        int c4 = i % (D / 4);
        int gr = row0 + r;
        const float* src = (gr < NTOK) ? (x + (size_t)gr * D)
                                       : (cb + (size_t)(gr - NTOK) * D);
        float4 v = ((const float4*)src)[c4];
        ((float4*)&As[r][0])[c4] = v;
    }
    __syncthreads();

    const int r = tid >> 4;          // 0..15
    const int c0 = (tid & 15) * 8;   // 0..120

    float acc[8];
#pragma unroll
    for (int j = 0; j < 8; j++) acc[j] = 0.f;

    for (int d = 0; d < D; d += 4) {
        float4 a4 = *(const float4*)&As[r][d];
#pragma unroll
        for (int dd = 0; dd < 4; dd++) {
            float av = (dd == 0) ? a4.x : (dd == 1) ? a4.y : (dd == 2) ? a4.z : a4.w;
            float4 w0 = *(const float4*)&w[(size_t)(d + dd) * P + c0];
            float4 w1 = *(const float4*)&w[(size_t)(d + dd) * P + c0 + 4];
            acc[0] = fmaf(av, w0.x, acc[0]);
            acc[1] = fmaf(av, w0.y, acc[1]);
            acc[2] = fmaf(av, w0.z, acc[2]);
            acc[3] = fmaf(av, w0.w, acc[3]);
            acc[4] = fmaf(av, w1.x, acc[4]);
            acc[5] = fmaf(av, w1.y, acc[5]);
            acc[6] = fmaf(av, w1.z, acc[6]);
            acc[7] = fmaf(av, w1.w, acc[7]);
        }
    }

    float out[8];
    float nrm = 0.f;
    u16x8 hv;
#pragma unroll
    for (int j = 0; j < 8; j++) {
        out[j] = acc[j] + bias[c0 + j];
        nrm = fmaf(out[j], out[j], nrm);
        hv[j] = f32_to_bf16_rne(out[j]);
    }

    const int gr = row0 + r;
    float4 o0; o0.x = out[0]; o0.y = out[1]; o0.z = out[2]; o0.w = out[3];
    float4 o1; o1.x = out[4]; o1.y = out[5]; o1.z = out[6]; o1.w = out[7];
    if (gr < NTOK) {
        float* dst = xproj + (size_t)gr * P;
        *(float4*)&dst[c0] = o0;
        *(float4*)&dst[c0 + 4] = o1;
        *(u16x8*)(xh + (size_t)gr * P + c0) = hv;
    } else {
        int row = gr - NTOK;
        float* dst = cproj + (size_t)row * P;
        *(float4*)&dst[c0] = o0;
        *(float4*)&dst[c0 + 4] = o1;
        int t64 = row >> 6, rg = (row >> 4) & 3, rl = row & 15;
        int ks = c0 >> 5, q = (c0 >> 3) & 3;
        size_t atom = ((size_t)(t64 * 16 + rg * 4 + ks) * 4 + q) * 16 + rl;
        *(u16x8*)(chs + atom * 8) = hv;
    }

#pragma unroll
    for (int off = 1; off < 16; off <<= 1)
        nrm += __shfl_xor(nrm, off, 16);
    if ((tid & 15) == 0) {
        if (gr < NTOK) xnorm[gr] = nrm;
        else           cnorm[gr - NTOK] = nrm;
    }
}

// ---------------------------------------------------------------------------
// Kernel 2: MFMA min pass + fused zero-fill. Hot loop has NO cross-lane ops,
// NO atomics, NO LDS: coalesced B loads -> MFMA -> register fmin, plus 8
// zero stores per tile using the latency bubbles. One butterfly at the end;
// publish per-token global bf16 min via int atomicMin (dist > 0).
// Block = 256 thr (4 waves) = 128 tokens x quarter-K; wave = 32 tokens.
// ---------------------------------------------------------------------------
__global__ __launch_bounds__(256, 3) void minzero_kernel(
    const unsigned short* __restrict__ xh, const unsigned short* __restrict__ chs,
    const float* __restrict__ xnorm, const float* __restrict__ cnorm,
    int* __restrict__ gmin, float* __restrict__ discrete)
{
    const int tid = threadIdx.x;
    const int tok0 = blockIdx.x * 128;
    const int kbase = blockIdx.y * 2048;
    const int flat = blockIdx.y * gridDim.x + blockIdx.x;   // 0..511

    const int wave = tid >> 6;
    const int lane = tid & 63;
    const int quad = lane >> 4;
    const int l15 = lane & 15;
    const int trow = tok0 + wave * 32;

    f32x4* zbase = (f32x4*)discrete + (size_t)flat * 65536;
    const f32x4 zv = (f32x4)(0.f);

    bf16x8 afrag[2][4];
#pragma unroll
    for (int mi = 0; mi < 2; mi++)
#pragma unroll
        for (int ks = 0; ks < 4; ks++)
            afrag[mi][ks] = *(const bf16x8*)(
                xh + (size_t)(trow + mi * 16 + l15) * P + ks * 32 + quad * 8);

    float xnv[2][4];
#pragma unroll
    for (int mi = 0; mi < 2; mi++)
#pragma unroll
        for (int r = 0; r < 4; r++)
            xnv[mi][r] = xnorm[trow + mi * 16 + quad * 4 + r];

    float rmin[2][4];
#pragma unroll
    for (int mi = 0; mi < 2; mi++)
#pragma unroll
        for (int r = 0; r < 4; r++) rmin[mi][r] = FLT_BIG;

    for (int ct = 0; ct < 32; ct++) {
        const int kt = kbase + ct * 64;
        const int t64 = kt >> 6;

#pragma unroll
        for (int s = 0; s < 8; s++)
            zbase[(size_t)ct * 2048 + s * 256 + tid] = zv;

        f32x4 acc[2][4];
#pragma unroll
        for (int mi = 0; mi < 2; mi++)
#pragma unroll
            for (int nj = 0; nj < 4; nj++) acc[mi][nj] = (f32x4)(0.f);

#pragma unroll
        for (int ks = 0; ks < 4; ks++) {
            const bf16x8* base = (const bf16x8*)(chs) + (size_t)(t64 * 16 + ks) * 64 + lane;
            bf16x8 b0 = base[0 * 4 * 64];
            bf16x8 b1 = base[1 * 4 * 64];
            bf16x8 b2 = base[2 * 4 * 64];
            bf16x8 b3 = base[3 * 4 * 64];
            acc[0][0] = __builtin_amdgcn_mfma_f32_16x16x32_bf16(afrag[0][ks], b0, acc[0][0], 0, 0, 0);
            acc[0][1] = __builtin_amdgcn_mfma_f32_16x16x32_bf16(afrag[0][ks], b1, acc[0][1], 0, 0, 0);
            acc[0][2] = __builtin_amdgcn_mfma_f32_16x16x32_bf16(afrag[0][ks], b2, acc[0][2], 0, 0, 0);
            acc[0][3] = __builtin_amdgcn_mfma_f32_16x16x32_bf16(afrag[0][ks], b3, acc[0][3], 0, 0, 0);
            acc[1][0] = __builtin_amdgcn_mfma_f32_16x16x32_bf16(afrag[1][ks], b0, acc[1][0], 0, 0, 0);
            acc[1][1] = __builtin_amdgcn_mfma_f32_16x16x32_bf16(afrag[1][ks], b1, acc[1][1], 0, 0, 0);
            acc[1][2] = __builtin_amdgcn_mfma_f32_16x16x32_bf16(afrag[1][ks], b2, acc[1][2], 0, 0, 0);
            acc[1][3] = __builtin_amdgcn_mfma_f32_16x16x32_bf16(afrag[1][ks], b3, acc[1][3], 0, 0, 0);
        }

        float cn[4];
#pragma unroll
        for (int nj = 0; nj < 4; nj++) cn[nj] = cnorm[kt + nj * 16 + l15];

#pragma unroll
        for (int mi = 0; mi < 2; mi++)
#pragma unroll
            for (int r = 0; r < 4; r++)
#pragma unroll
                for (int nj = 0; nj < 4; nj++) {
                    float dd = (xnv[mi][r] - 2.0f * acc[mi][nj][r]) + cn[nj];
                    rmin[mi][r] = fminf(rmin[mi][r], dd);
                }
    }

#pragma unroll
    for (int mi = 0; mi < 2; mi++)
#pragma unroll
        for (int r = 0; r < 4; r++) {
            float m = rmin[mi][r];
#pragma unroll
            for (int off = 1; off < 16; off <<= 1)
                m = fminf(m, __shfl_xor(m, off));
            if (l15 == 0)
                atomicMin(&gmin[trow + mi * 16 + quad * 4 + r], __float_as_int(m));
        }
}

// ---------------------------------------------------------------------------
// Kernel 3: collect pass. Identical distance loop against the FIXED
// threshold gmin + MARGIN (kernel boundary guarantees gmin visibility).
// Superset of fp32 argmin: d_bf16(k*) <= gmin + 2eps < gmin + MARGIN.
// Expected ~1-3 emissions per token.
// ---------------------------------------------------------------------------
__global__ __launch_bounds__(256, 3) void collect_kernel(
    const unsigned short* __restrict__ xh, const unsigned short* __restrict__ chs,
    const float* __restrict__ xnorm, const float* __restrict__ cnorm,
    const int* __restrict__ gmin,
    int* __restrict__ cnt, int* __restrict__ cand)
{
    const int tid = threadIdx.x;
    const int tok0 = blockIdx.x * 128;
    const int kbase = blockIdx.y * 2048;

    const int wave = tid >> 6;
    const int lane = tid & 63;
    const int quad = lane >> 4;
    const int l15 = lane & 15;
    const int trow = tok0 + wave * 32;

    bf16x8 afrag[2][4];
#pragma unroll
    for (int mi = 0; mi < 2; mi++)
#pragma unroll
        for (int ks = 0; ks < 4; ks++)
            afrag[mi][ks] = *(const bf16x8*)(
                xh + (size_t)(trow + mi * 16 + l15) * P + ks * 32 + quad * 8);

    float xnv[2][4], thr[2][4];
#pragma unroll
    for (int mi = 0; mi < 2; mi++)
#pragma unroll
        for (int r = 0; r < 4; r++) {
            int t = trow + mi * 16 + quad * 4 + r;
            xnv[mi][r] = xnorm[t];
            thr[mi][r] = __int_as_float(gmin[t]) + MARGIN;
        }

    for (int ct = 0; ct < 32; ct++) {
        const int kt = kbase + ct * 64;
        const int t64 = kt >> 6;

        f32x4 acc[2][4];
#pragma unroll
        for (int mi = 0; mi < 2; mi++)
#pragma unroll
            for (int nj = 0; nj < 4; nj++) acc[mi][nj] = (f32x4)(0.f);

#pragma unroll
        for (int ks = 0; ks < 4; ks++) {
            const bf16x8* base = (const bf16x8*)(chs) + (size_t)(t64 * 16 + ks) * 64 + lane;
            bf16x8 b0 = base[0 * 4 * 64];
            bf16x8 b1 = base[1 * 4 * 64];
            bf16x8 b2 = base[2 * 4 * 64];
            bf16x8 b3 = base[3 * 4 * 64];
            acc[0][0] = __builtin_amdgcn_mfma_f32_16x16x32_bf16(afrag[0][ks], b0, acc[0][0], 0, 0, 0);
            acc[0][1] = __builtin_amdgcn_mfma_f32_16x16x32_bf16(afrag[0][ks], b1, acc[0][1], 0, 0, 0);
            acc[0][2] = __builtin_amdgcn_mfma_f32_16x16x32_bf16(afrag[0][ks], b2, acc[0][2], 0, 0, 0);
            acc[0][3] = __builtin_amdgcn_mfma_f32_16x16x32_bf16(afrag[0][ks], b3, acc[0][3], 0, 0, 0);
            acc[1][0] = __builtin_amdgcn_mfma_f32_16x16x32_bf16(afrag[1][ks], b0, acc[1][0], 0, 0, 0);
            acc[1][1] = __builtin_amdgcn_mfma_f32_16x16x32_bf16(afrag[1][ks], b1, acc[1][1], 0, 0, 0);
            acc[1][2] = __builtin_amdgcn_mfma_f32_16x16x32_bf16(afrag[1][ks], b2, acc[1][2], 0, 0, 0);
            acc[1][3] = __builtin_amdgcn_mfma_f32_16x16x32_bf16(afrag[1][ks], b3, acc[1][3], 0, 0, 0);
        }

        float cn[4];
#pragma unroll
        for (int nj = 0; nj < 4; nj++) cn[nj] = cnorm[kt + nj * 16 + l15];

#pragma unroll
        for (int mi = 0; mi < 2; mi++)
#pragma unroll
            for (int r = 0; r < 4; r++) {
                const int tok = trow + mi * 16 + quad * 4 + r;
#pragma unroll
                for (int nj = 0; nj < 4; nj++) {
                    float dd = (xnv[mi][r] - 2.0f * acc[mi][nj][r]) + cn[nj];
                    if (dd <= thr[mi][r]) {
                        int pos = atomicAdd(&cnt[tok], 1);
                        if (pos < CAPC) cand[(size_t)tok * CAPC + pos] = kt + nj * 16 + l15;
                    }
                }
            }
    }
}

// ---------------------------------------------------------------------------
// Kernel 4: fused exact-fp32 rescore + argmin + one-hot scatter + gather
// (proven round 9). Packed u64 (dist_bits<<32|k): dist>0 -> monotone bits;
// tie -> lower idx (= jnp.argmin). Bit-identical serial-fma order.
// ---------------------------------------------------------------------------
__global__ __launch_bounds__(256) void rescorefinal_kernel(
    const float* __restrict__ xproj, const float* __restrict__ cproj,
    const float* __restrict__ xnorm, const float* __restrict__ cnorm,
    const int* __restrict__ cnt, const int* __restrict__ cand,
    const float* __restrict__ cb,
    float* __restrict__ discrete, float* __restrict__ quant)
{
    __shared__ int sidx[64];
    const int tid = threadIdx.x;
    const int lane = tid & 63;
    const int wave = tid >> 6;
    const int tok0 = blockIdx.x * 64;

    for (int i = 0; i < 16; i++) {
        const int t = tok0 + wave * 16 + i;
        int n = cnt[t];
        if (n > CAPC) n = CAPC;
        const float xn = xnorm[t];
        const float* xr = xproj + (size_t)t * P;

        unsigned long long pack = 0xFFFFFFFFFFFFFFFFull;
        for (int j = lane; j < n; j += 64) {
            int k = cand[(size_t)t * CAPC + j];
            const float* cr = cproj + (size_t)k * P;
            float s = 0.f;
#pragma unroll 8
            for (int p = 0; p < P; p += 4) {
                float4 a = *(const float4*)&xr[p];
                float4 b = *(const float4*)&cr[p];
                s = fmaf(a.x, b.x, s);
                s = fmaf(a.y, b.y, s);
                s = fmaf(a.z, b.z, s);
                s = fmaf(a.w, b.w, s);
            }
            float dist = (xn - 2.0f * s) + cnorm[k];
            unsigned long long pk =
                ((unsigned long long)__float_as_uint(dist) << 32) |
                (unsigned long long)(unsigned)k;
            if (pk < pack) pack = pk;
        }
#pragma unroll
        for (int off = 1; off < 64; off <<= 1) {
            unsigned long long o = __shfl_xor((long long)pack, off);
            if (o < pack) pack = o;
        }
        if (lane == 0) {
            int bi = (int)(pack & 0xFFFFFFFFull);
            if (bi >= 0 && bi < K) {
                sidx[wave * 16 + i] = bi;
                discrete[(size_t)t * K + bi] = 1.0f;
            } else sidx[wave * 16 + i] = 0;
        }
    }
    __syncthreads();

    for (int i = tid; i < 64 * (D / 4); i += 256) {
        int t = i >> 6;
        int c4 = i & 63;
        int bi = sidx[t];
        float4 v = ((const float4*)(cb + (size_t)bi * D))[c4];
        ((float4*)(quant + (size_t)(tok0 + t) * D))[c4] = v;
    }
}

// ---------------------------------------------------------------------------
extern "C" void kernel_launch(void* const* d_in, const int* in_sizes, int n_in,
                              void* d_out, int out_size, void* d_ws, size_t ws_size,
                              hipStream_t stream) {
    const float* x    = (const float*)d_in[0];   // [16,1024,256]
    const float* cb   = (const float*)d_in[1];   // [8192,256]
    const float* w    = (const float*)d_in[2];   // [256,128]
    const float* bias = (const float*)d_in[3];   // [128]

    float* out = (float*)d_out;
    float* discrete = out;                               // [16384, 8192]
    float* quant = out + (size_t)NTOK * K;               // [16384, 256]

    char* ws = (char*)d_ws;
    size_t off = 0;
    float* xproj = (float*)(ws + off); off += (size_t)NTOK * P * 4;
    float* cproj = (float*)(ws + off); off += (size_t)K * P * 4;
    float* xnorm = (float*)(ws + off); off += (size_t)NTOK * 4;
    float* cnorm = (float*)(ws + off); off += (size_t)K * 4;
    unsigned short* xh  = (unsigned short*)(ws + off); off += (size_t)NTOK * P * 2;
    unsigned short* chs = (unsigned short*)(ws + off); off += (size_t)K * P * 2;
    int* cnt  = (int*)(ws + off); off += (size_t)NTOK * 4;
    int* cand = (int*)(ws + off); off += (size_t)NTOK * CAPC * 4;
    int* gmin = (int*)(ws + off); off += (size_t)NTOK * 4;

    proj_kernel<<<dim3(NROWS / 16), dim3(256), 0, stream>>>(
        x, cb, w, bias, xproj, cproj, xnorm, cnorm, xh, chs, cnt, gmin);

    minzero_kernel<<<dim3(NTOK / 128, 4), dim3(256), 0, stream>>>(
        xh, chs, xnorm, cnorm, gmin, discrete);

    collect_kernel<<<dim3(NTOK / 128, 4), dim3(256), 0, stream>>>(
        xh, chs, xnorm, cnorm, gmin, cnt, cand);

    rescorefinal_kernel<<<dim3(NTOK / 64), dim3(256), 0, stream>>>(
        xproj, cproj, xnorm, cnorm, cnt, cand, cb, discrete, quant);
}